// Round 11
// baseline (540.979 us; speedup 1.0000x reference)
//
#include <hip/hip_runtime.h>
#include <hip/hip_cooperative_groups.h>

namespace cg = cooperative_groups;

typedef _Float16 f16;
typedef _Float16 f16x8 __attribute__((ext_vector_type(8)));
typedef _Float16 f16x4 __attribute__((ext_vector_type(4)));
typedef float f32x4 __attribute__((ext_vector_type(4)));

#define MFMA16(A, B, C) __builtin_amdgcn_mfma_f32_16x16x32_f16((A), (B), (C), 0, 0, 0)

// async global->LDS, 16B per lane, dest = wave-uniform base + lane*16
__device__ __forceinline__ void async16(void* lds, const void* gp) {
    __builtin_amdgcn_global_load_lds(
        (__attribute__((address_space(1))) void*)(gp),
        (__attribute__((address_space(3))) void*)(lds), 16, 0, 0);
}

// ---- shared-memory union: every stage fits in 32 KiB -> 4 blocks/CU if VGPR<=128 ----
union SMem {
    struct { f16 Ks[2 * 64 * 64]; f16 Vs[2 * 64 * 64]; } a;  // attn: 32768 B
    struct { f16 As[2 * 128 * 32]; f16 Bs[2 * 128 * 32]; } g;  // gemm: 32768 B
    float wtile[32][33];                                        // weight transpose
    f16 vtile[32][33];                                          // V transpose
};

// ---------------- GEMM tile body: 128x128, BK=32, 2-buffer async-LDS pipeline ----------
// (verified round 7 as k_gemm_bt v2; identical math/layout, LDS passed in)
template <bool OUT_F16>
__device__ __forceinline__ void gemm_tile(const f16* __restrict__ A,
                                          const f16* __restrict__ Bt,
                                          void* __restrict__ Cv,
                                          int N, int K, int m0, int n0,
                                          f16* As, f16* Bs, int t) {
    int lane = t & 63, w = t >> 6;
    int wm = (w >> 1) * 64, wn = (w & 1) * 64;
    int ln = lane & 15, g = lane >> 4;

    int lin0 = w * 128 + lane, lin1 = lin0 + 64;
    int r0 = lin0 >> 2, c0 = (lin0 & 3) ^ ((r0 >> 1) & 3);
    int r1 = lin1 >> 2, c1 = (lin1 & 3) ^ ((r1 >> 1) & 3);
    const f16* gA0 = A + (size_t)(m0 + r0) * K + c0 * 8;
    const f16* gA1 = A + (size_t)(m0 + r1) * K + c1 * 8;
    const f16* gB0 = Bt + (size_t)(n0 + r0) * K + c0 * 8;
    const f16* gB1 = Bt + (size_t)(n0 + r1) * K + c1 * 8;

    f32x4 acc[4][4] = {};
    int sw = (ln >> 1) & 3;

#define GISSUE(bi, kk)                                \
    do {                                              \
        f16* lA = As + (bi) * 4096 + w * 1024;        \
        f16* lB = Bs + (bi) * 4096 + w * 1024;        \
        async16(lA, gA0 + (kk));                      \
        async16(lA + 512, gA1 + (kk));                \
        async16(lB, gB0 + (kk));                      \
        async16(lB + 512, gB1 + (kk));                \
    } while (0)

    GISSUE(0, 0);
    __syncthreads();  // drains vmcnt -> tile 0 staged

    int cur = 0;
    for (int k0 = 0; k0 < K; k0 += 32) {
        if (k0 + 32 < K) GISSUE(cur ^ 1, k0 + 32);
        f16x8 af[4], bf[4];
#pragma unroll
        for (int i = 0; i < 4; i++) {
            af[i] = *(const f16x8*)(As + cur * 4096 + (wm + i * 16 + ln) * 32 + (g ^ sw) * 8);
            bf[i] = *(const f16x8*)(Bs + cur * 4096 + (wn + i * 16 + ln) * 32 + (g ^ sw) * 8);
        }
#pragma unroll
        for (int mt = 0; mt < 4; mt++)
#pragma unroll
            for (int nt = 0; nt < 4; nt++)
                acc[mt][nt] = MFMA16(af[mt], bf[nt], acc[mt][nt]);
        __syncthreads();  // drains next-tile staging; all waves done reading cur
        cur ^= 1;
    }
#undef GISSUE

    int rg = g * 4;
#pragma unroll
    for (int mt = 0; mt < 4; mt++)
#pragma unroll
        for (int nt = 0; nt < 4; nt++)
#pragma unroll
            for (int r = 0; r < 4; r++) {
                int row = m0 + wm + mt * 16 + rg + r;
                int col = n0 + wn + nt * 16 + ln;
                float v = acc[mt][nt][r];
                if (OUT_F16)
                    ((f16*)Cv)[(size_t)row * N + col] = (f16)v;
                else
                    ((float*)Cv)[(size_t)row * N + col] = v;
            }
}

// ---------------- attention unit body: in-register P, async-LDS dbuf, split-k ----------
// (verified rounds 6-10 as k_attn v9; identical math/layout, LDS passed in)
__device__ __forceinline__ void attn_unit(const f16* __restrict__ QKV,
                                          const f16* __restrict__ Vt,
                                          f16* __restrict__ Opart,
                                          float* __restrict__ Rsum,
                                          int bh, int pi, f16* Ks, f16* Vs, int t) {
    int b = bh >> 4, h = bh & 15;
    int lane = t & 63, wq = t >> 6;
    int ln = lane & 15, g = lane >> 4, g8 = g * 8, rg = g * 4;
    int sx = ln & 7;  // read-side chunk xor

    int r0 = wq * 8 + (lane >> 3);        // phys row for instr 0 (0..31)
    int cp = lane & 7;
    int cl = (cp ^ (r0 & 7)) * 8;         // logical col (f16 elems) to fetch
    int gk0 = ((r0 & 16) >> 2) | ((r0 & 12) << 1) | (r0 & 3);  // glob(r0)
    const f16* Kb = QKV + (size_t)b * 2048 * 3072 + 1024 + h * 64;
    const f16* Vb = Vt + (size_t)bh * 64 * 2048;
    const f16* gK0 = Kb + (size_t)gk0 * 3072 + cl;
    const f16* gK1 = Kb + (size_t)(gk0 + 32) * 3072 + cl;
    const f16* gV0 = Vb + (size_t)r0 * 2048 + cl;
    const f16* gV1 = Vb + (size_t)(r0 + 32) * 2048 + cl;

    const float C_SCL = 0.18033688f;   // 0.125 * log2(e)
    const float C_MSK = -72.134752f;   // -50 * log2(e)
    f16x8 ones;
#pragma unroll
    for (int j = 0; j < 8; j++) ones[j] = (f16)1.f;

    int nk0 = 16 - pi;  // phase-0 tile count; total tiles always 17

#define ISSUE(bi, j)                                                      \
    do {                                                                  \
        int jj = (j);                                                     \
        int kt_ = (jj < nk0) ? jj : jj - nk0 + pi + 1;                    \
        size_t kO = (size_t)kt_ * 64;                                     \
        async16(Ks + (bi) * 4096 + wq * 512, gK0 + kO * 3072);            \
        async16(Ks + (bi) * 4096 + 2048 + wq * 512, gK1 + kO * 3072);     \
        async16(Vs + (bi) * 4096 + wq * 512, gV0 + kO);                   \
        async16(Vs + (bi) * 4096 + 2048 + wq * 512, gV1 + kO);            \
    } while (0)

    ISSUE(0, 0);
    __syncthreads();  // barrier drains vmcnt -> tile 0 staged

    int i = 0;
    for (int phase = 0; phase < 2; phase++) {
        int qt  = phase ? pi : 15 - pi;
        int ktB = phase ? pi + 1 : 0;
        int ktE = phase ? 2 * pi + 2 : 16 - pi;
        int q0 = qt * 128;

        f16x8 bq[2][2];
#pragma unroll
        for (int nt = 0; nt < 2; nt++)
#pragma unroll
            for (int kd = 0; kd < 2; kd++)
                bq[nt][kd] = *(const f16x8*)(QKV +
                    (size_t)(b * 2048 + q0 + wq * 32 + nt * 16 + ln) * 3072 +
                    h * 64 + kd * 32 + g8);

        f32x4 oacc[2][4] = {};
        f32x4 osum[2] = {};

        for (int kt = ktB; kt < ktE; kt++, i++) {
            int cur = i & 1;
            int k0 = kt * 64;
            bool active = (k0 <= q0 + wq * 32 + 31);  // wave-uniform

            if (i + 1 < 17) ISSUE(cur ^ 1, i + 1);

            if (active) {
                f16x8 ak[2][4];
#pragma unroll
                for (int kd = 0; kd < 2; kd++)
#pragma unroll
                    for (int mt = 0; mt < 4; mt++)
                        ak[kd][mt] = *(const f16x8*)(Ks + cur * 4096 +
                            (mt * 16 + ln) * 64 + (((kd * 4 + g) ^ sx) * 8));
                f32x4 sacc[4][2] = {};
#pragma unroll
                for (int kd = 0; kd < 2; kd++)
#pragma unroll
                    for (int mt = 0; mt < 4; mt++)
#pragma unroll
                        for (int nt = 0; nt < 2; nt++)
                            sacc[mt][nt] = MFMA16(ak[kd][mt], bq[nt][kd], sacc[mt][nt]);

                bool needs_mask = (k0 + 63 > q0 + wq * 32);
                f16x8 ap[2][2];
#pragma unroll
                for (int nt = 0; nt < 2; nt++) {
                    int q = q0 + wq * 32 + nt * 16 + ln;
#pragma unroll
                    for (int mt = 0; mt < 4; mt++) {
                        int kb = mt >> 1, hi4 = (mt & 1) * 4;
#pragma unroll
                        for (int r = 0; r < 4; r++) {
                            float e;
                            if (needs_mask) {
                                int kk = k0 + kb * 32 + hi4 + 8 * g + r;
                                e = __builtin_amdgcn_exp2f(
                                    fmaf(sacc[mt][nt][r], C_SCL, (kk > q) ? C_MSK : 0.f));
                            } else {
                                e = __builtin_amdgcn_exp2f(sacc[mt][nt][r] * C_SCL);
                            }
                            ap[nt][kb][hi4 + r] = (f16)e;
                        }
                    }
                }

#pragma unroll
                for (int kk = 0; kk < 2; kk++) {
                    f16x8 bv[4];
#pragma unroll
                    for (int dt = 0; dt < 4; dt++)
                        bv[dt] = *(const f16x8*)(Vs + cur * 4096 +
                            (dt * 16 + ln) * 64 + (((kk * 4 + g) ^ sx) * 8));
#pragma unroll
                    for (int nt = 0; nt < 2; nt++) {
#pragma unroll
                        for (int dt = 0; dt < 4; dt++)
                            oacc[nt][dt] = MFMA16(ap[nt][kk], bv[dt], oacc[nt][dt]);
                        osum[nt] = MFMA16(ap[nt][kk], ones, osum[nt]);
                    }
                }
            }
            __syncthreads();  // drains tile i+1 staging; all waves done reading cur
        }

        int u = (bh * 16 + qt) * 2 + phase;
#pragma unroll
        for (int nt = 0; nt < 2; nt++)
#pragma unroll
            for (int r = 0; r < 4; r++) {
                float rs = osum[nt][r];
                float inv = __builtin_amdgcn_rcpf(fmaxf(rs, 1e-30f));
                int q = wq * 32 + nt * 16 + rg + r;
                if (ln == 0) Rsum[u * 128 + q] = rs;
#pragma unroll
                for (int dt = 0; dt < 4; dt++)
                    Opart[(size_t)u * 8192 + q * 64 + dt * 16 + ln] =
                        (f16)(oacc[nt][dt][r] * inv);
            }
    }
#undef ISSUE
}

// ---------------- mega kernel: all six stages, grid.sync between them ------------------
// Every stage is a grid-stride loop -> correct for ANY grid size; host picks
// grid = min(1024, occupancy-capacity) so the cooperative launch cannot over-subscribe.
// Stage math is byte-identical to the round-8/10 verified kernels.
__global__ __launch_bounds__(256, 2) void k_mega(
    const float* __restrict__ x, const float* __restrict__ Wq,
    const float* __restrict__ Wk, const float* __restrict__ Wv,
    const float* __restrict__ Wr, float* __restrict__ out,
    f16* __restrict__ xb, f16* __restrict__ Wqkvt, f16* __restrict__ Wrt,
    f16* __restrict__ QKVb, f16* __restrict__ Vtb, f16* __restrict__ Obuf,
    f16* __restrict__ Opart, float* __restrict__ Rsum) {
    __shared__ SMem sm;
    cg::grid_group grid = cg::this_grid();
    int t = threadIdx.x;

    // ---- stage 1: prep (cast x; transpose-cast 4 weights). 12288 virtual blocks ----
    for (int vb = blockIdx.x; vb < 12288; vb += gridDim.x) {
        if (vb < 8192) {
            int i = (vb * 256 + t) * 4;
            float4 v = *(const float4*)(x + i);
            f16x4 o = {(f16)v.x, (f16)v.y, (f16)v.z, (f16)v.w};
            *(f16x4*)(xb + i) = o;
        } else {
            int wid = vb - 8192;  // [0,4096)
            int z = wid >> 10;
            int tid = wid & 1023;
            const float* W = (z == 0) ? Wq : (z == 1) ? Wk : (z == 2) ? Wv : Wr;
            f16* Wt = (z == 3) ? Wrt : Wqkvt + z * 1048576;
            int c0 = (tid & 31) * 32, rr0 = (tid >> 5) * 32;
            int tx = t & 31, ty = t >> 5;  // 32 x 8
#pragma unroll
            for (int j = 0; j < 32; j += 8)
                sm.wtile[ty + j][tx] = W[(rr0 + ty + j) * 1024 + c0 + tx];
            __syncthreads();
#pragma unroll
            for (int j = 0; j < 32; j += 8)
                Wt[(c0 + ty + j) * 1024 + rr0 + tx] = (f16)sm.wtile[tx][ty + j];
            __syncthreads();  // tile reused next iteration
        }
    }
    grid.sync();

    // ---- stage 2: QKV projection GEMM. 24x64 = 1536 virtual tiles ----
    for (int vt = blockIdx.x; vt < 1536; vt += gridDim.x) {
        int n0 = (vt % 24) * 128;
        int m0 = (vt / 24) * 128;
        gemm_tile<true>(xb, Wqkvt, QKVb, 3072, 1024, m0, n0, sm.g.As, sm.g.Bs, t);
    }
    grid.sync();

    // ---- stage 3: transpose V slice into Vt[bh][d][s]. 8192 virtual blocks ----
    for (int vb = blockIdx.x; vb < 8192; vb += gridDim.x) {
        int s0 = (vb & 63) * 32;
        int d0 = ((vb >> 6) & 1) * 32;
        int bh = vb >> 7;
        int b = bh >> 4, h = bh & 15;
        int tx = t & 31, ty = t >> 5;  // 32 x 8
#pragma unroll
        for (int j = 0; j < 32; j += 8)
            sm.vtile[ty + j][tx] =
                QKVb[(b * 2048 + s0 + ty + j) * 3072 + 2048 + h * 64 + d0 + tx];
        __syncthreads();
#pragma unroll
        for (int j = 0; j < 32; j += 8)
            Vtb[(size_t)(bh * 64 + d0 + ty + j) * 2048 + s0 + tx] = sm.vtile[tx][ty + j];
        __syncthreads();  // tile reused next iteration
    }
    grid.sync();

    // ---- stage 4: attention. 1024 units (bh fastest for L2 locality) ----
    for (int vb = blockIdx.x; vb < 1024; vb += gridDim.x) {
        attn_unit(QKVb, Vtb, Opart, Rsum, vb & 63, vb >> 6, sm.a.Ks, sm.a.Vs, t);
    }
    grid.sync();

    // ---- stage 5: merge split-k partials. 4096 virtual blocks ----
    for (int vb = blockIdx.x; vb < 4096; vb += gridDim.x) {
        int idx = vb * 256 + t;
        int d8 = idx & 7;
        int q  = (idx >> 3) & 127;
        int qt = (idx >> 10) & 15;
        int bh = idx >> 14;
        int b = bh >> 4, hd = bh & 15;
        int u0 = (bh * 16 + qt) * 2;
        float rs0 = Rsum[u0 * 128 + q], rs1 = Rsum[(u0 + 1) * 128 + q];
        float inv = __builtin_amdgcn_rcpf(rs0 + rs1);
        f16x8 o0 = *(const f16x8*)(Opart + (size_t)u0 * 8192 + q * 64 + d8 * 8);
        f16x8 o1 = *(const f16x8*)(Opart + (size_t)(u0 + 1) * 8192 + q * 64 + d8 * 8);
        f16x8 o;
#pragma unroll
        for (int j = 0; j < 8; j++)
            o[j] = (f16)((rs0 * (float)o0[j] + rs1 * (float)o1[j]) * inv);
        *(f16x8*)(Obuf + (size_t)(b * 2048 + qt * 128 + q) * 1024 + hd * 64 + d8 * 8) = o;
    }
    grid.sync();

    // ---- stage 6: output projection GEMM (fp32 out). 8x64 = 512 virtual tiles ----
    for (int vt = blockIdx.x; vt < 512; vt += gridDim.x) {
        int n0 = (vt % 8) * 128;
        int m0 = (vt / 8) * 128;
        gemm_tile<false>(Obuf, Wrt, out, 1024, 1024, m0, n0, sm.g.As, sm.g.Bs, t);
    }
}

// ---------------- host launch ----------------
extern "C" void kernel_launch(void* const* d_in, const int* in_sizes, int n_in,
                              void* d_out, int out_size, void* d_ws, size_t ws_size,
                              hipStream_t stream) {
    const float* x = (const float*)d_in[0];
    const float* Wq = (const float*)d_in[1];
    const float* Wk = (const float*)d_in[2];
    const float* Wv = (const float*)d_in[3];
    const float* Wr = (const float*)d_in[4];
    float* out = (float*)d_out;

    f16* ws = (f16*)d_ws;
    f16* xb    = ws;                    // 8192*1024
    f16* Wqkvt = xb + 8388608;          // 3072*1024
    f16* Wrt   = Wqkvt + 3145728;       // 1024*1024
    f16* QKVb  = Wrt + 1048576;         // 8192*3072
    f16* Vtb   = QKVb + 25165824;       // 64bh * 64d * 2048s
    f16* Obuf  = Vtb + 8388608;         // 8192*1024
    f16* Opart = Obuf + 8388608;        // 2048 units * 128q * 64d
    float* Rsum = (float*)(Opart + 16777216);  // 2048 units * 128q

    // grid = min(1024, co-residency capacity); stages are grid-stride so any grid works.
    static int nblk = 0;
    if (nblk == 0) {
        int bpc = 0;
        hipOccupancyMaxActiveBlocksPerMultiprocessor(&bpc, k_mega, 256, 0);
        if (bpc < 1) bpc = 1;
        long cap = (long)bpc * 256;  // 256 CUs on MI355X
        nblk = (int)(cap < 1024 ? cap : 1024);
    }

    void* args[] = {&x, &Wq, &Wk, &Wv, &Wr, &out, &xb, &Wqkvt, &Wrt,
                    &QKVb, &Vtb, &Obuf, &Opart, &Rsum};
    hipLaunchCooperativeKernel((const void*)k_mega, dim3(nblk), dim3(256), args, 0, stream);
}

// Round 13
// 274.249 us; speedup vs baseline: 1.9726x; 1.9726x over previous
//
#include <hip/hip_runtime.h>

typedef _Float16 f16;
typedef _Float16 f16x8 __attribute__((ext_vector_type(8)));
typedef _Float16 f16x4 __attribute__((ext_vector_type(4)));
typedef float f32x4 __attribute__((ext_vector_type(4)));

#define MFMA16(A, B, C) __builtin_amdgcn_mfma_f32_16x16x32_f16((A), (B), (C), 0, 0, 0)

// async global->LDS, 16B per lane, dest = wave-uniform base + lane*16
__device__ __forceinline__ void async16(void* lds, const void* gp) {
    __builtin_amdgcn_global_load_lds(
        (__attribute__((address_space(1))) void*)(gp),
        (__attribute__((address_space(3))) void*)(lds), 16, 0, 0);
}

// ---------------- fused prep: fp32->fp16 cast of x  +  transpose-cast of 4 weights -----
__global__ __launch_bounds__(256) void k_prep(const float* __restrict__ x,
                                              const float* __restrict__ Wq,
                                              const float* __restrict__ Wk,
                                              const float* __restrict__ Wv,
                                              const float* __restrict__ Wr,
                                              f16* __restrict__ xb,
                                              f16* __restrict__ Wqkvt,
                                              f16* __restrict__ Wrt) {
    __shared__ float tile[32][33];
    int bid = blockIdx.x;
    if (bid < 8192) {
        int i = (bid * 256 + threadIdx.x) * 4;  // 8192*256*4 = 8388608 exactly
        float4 v = *(const float4*)(x + i);
        f16x4 o = {(f16)v.x, (f16)v.y, (f16)v.z, (f16)v.w};
        *(f16x4*)(xb + i) = o;
    } else {
        int wid = bid - 8192;  // [0,4096)
        int z = wid >> 10;
        int tid = wid & 1023;
        const float* W = (z == 0) ? Wq : (z == 1) ? Wk : (z == 2) ? Wv : Wr;
        f16* Wt = (z == 3) ? Wrt : Wqkvt + z * 1048576;
        int c0 = (tid & 31) * 32, r0 = (tid >> 5) * 32;
        int tx = threadIdx.x & 31, ty = threadIdx.x >> 5;  // 32 x 8
#pragma unroll
        for (int j = 0; j < 32; j += 8)
            tile[ty + j][tx] = W[(r0 + ty + j) * 1024 + c0 + tx];
        __syncthreads();
#pragma unroll
        for (int j = 0; j < 32; j += 8)
            Wt[(c0 + ty + j) * 1024 + r0 + tx] = (f16)tile[tx][ty + j];
    }
}

// ---------------- transpose V slice of QKV into Vt[bh][d][s] ----------------
__global__ __launch_bounds__(256) void k_transpose_v(const f16* __restrict__ QKV,
                                                     f16* __restrict__ Vt) {
    __shared__ f16 tile[32][33];
    int s0 = blockIdx.x * 32;
    int d0 = blockIdx.y * 32;
    int bh = blockIdx.z;
    int b = bh >> 4, h = bh & 15;
    int tx = threadIdx.x, ty = threadIdx.y;  // 32 x 8
#pragma unroll
    for (int j = 0; j < 32; j += 8)
        tile[ty + j][tx] = QKV[(b * 2048 + s0 + ty + j) * 3072 + 2048 + h * 64 + d0 + tx];
    __syncthreads();
#pragma unroll
    for (int j = 0; j < 32; j += 8)
        Vt[(bh * 64 + d0 + ty + j) * 2048 + s0 + tx] = tile[tx][ty + j];
}

// ---------------- GEMM v4: BMx128 tile, BK=32, 3-buffer 2-deep counted-vmcnt pipeline ---
// BM=128 instantiation is byte-identical in structure to the round-8 verified kernel.
// BM=64 doubles block count for the small output GEMM (512->1024 blocks, 4/CU).
// Counted-vmcnt ledger: in-flight loads/thread/tile = BM/64 + 2 -> vmcnt(4)@BM128,
// vmcnt(3)@BM64; tile i+1's loads stay in flight across the barrier (T4). Raw s_barrier
// so the compiler doesn't re-insert a vmcnt(0) drain. WAR: buf (i+2)%3 last read before
// the previous barrier. Swizzle invariant: (row>>1)&3 == (ln>>1)&3 holds for both BM
// (wm stays a multiple of 32).
template <bool OUT_F16, int BM>
__global__ __launch_bounds__(256) void k_gemm_bt(const f16* __restrict__ A,
                                                 const f16* __restrict__ Bt,
                                                 void* __restrict__ Cv,
                                                 int M, int N, int K) {
    constexpr int MT = BM / 32;   // M fragments per wave
    constexpr int PT = BM / 64;   // A staging chunks per thread (1 or 2)
    __shared__ f16 As[3][BM][32];
    __shared__ f16 Bs[3][128][32];
    int t = threadIdx.x;
    int lane = t & 63, w = t >> 6;
    int wm = (w >> 1) * (BM / 2), wn = (w & 1) * 64;
    int m0 = blockIdx.y * BM, n0 = blockIdx.x * 128;
    int ln = lane & 15, g = lane >> 4;

    // A staging map: PT 64-chunk instructions per wave
    int linA0 = w * 64 * PT + lane;
    int rA0 = linA0 >> 2, cA0 = (linA0 & 3) ^ ((rA0 >> 1) & 3);
    int linA1 = linA0 + 64;
    int rA1 = linA1 >> 2, cA1 = (linA1 & 3) ^ ((rA1 >> 1) & 3);
    // B staging map: two 64-chunk instructions per wave (always 128 rows)
    int linB0 = w * 128 + lane, linB1 = linB0 + 64;
    int rB0 = linB0 >> 2, cB0 = (linB0 & 3) ^ ((rB0 >> 1) & 3);
    int rB1 = linB1 >> 2, cB1 = (linB1 & 3) ^ ((rB1 >> 1) & 3);
    const f16* gA0 = A + (size_t)(m0 + rA0) * K + cA0 * 8;
    const f16* gA1 = A + (size_t)(m0 + rA1) * K + cA1 * 8;
    const f16* gB0 = Bt + (size_t)(n0 + rB0) * K + cB0 * 8;
    const f16* gB1 = Bt + (size_t)(n0 + rB1) * K + cB1 * 8;

    f32x4 acc[MT][4] = {};
    int sw = (ln >> 1) & 3;

#define GISSUE(bi, kk)                                          \
    do {                                                        \
        f16* lA = &As[0][0][0] + (bi) * (BM * 32) + w * 512 * PT; \
        f16* lB = &Bs[0][0][0] + (bi) * 4096 + w * 1024;        \
        async16(lA, gA0 + (kk));                                \
        if (PT == 2) async16(lA + 512, gA1 + (kk));             \
        async16(lB, gB0 + (kk));                                \
        async16(lB + 512, gB1 + (kk));                          \
    } while (0)

    GISSUE(0, 0);
    GISSUE(1, 32);

    int b0 = 0, b1 = 1, b2 = 2;
    for (int k0 = 0; k0 < K; k0 += 32) {
        if (k0 + 32 < K) {
            if (PT == 2)
                asm volatile("s_waitcnt vmcnt(4) lgkmcnt(0)" ::: "memory");
            else
                asm volatile("s_waitcnt vmcnt(3) lgkmcnt(0)" ::: "memory");
        } else {
            asm volatile("s_waitcnt vmcnt(0) lgkmcnt(0)" ::: "memory");
        }
        __builtin_amdgcn_s_barrier();
        __builtin_amdgcn_sched_barrier(0);
        if (k0 + 64 < K) GISSUE(b2, k0 + 64);

        f16x8 af[MT], bf[4];
#pragma unroll
        for (int i = 0; i < MT; i++)
            af[i] = *(const f16x8*)&As[b0][wm + i * 16 + ln][(g ^ sw) * 8];
#pragma unroll
        for (int i = 0; i < 4; i++)
            bf[i] = *(const f16x8*)&Bs[b0][wn + i * 16 + ln][(g ^ sw) * 8];
#pragma unroll
        for (int mt = 0; mt < MT; mt++)
#pragma unroll
            for (int nt = 0; nt < 4; nt++)
                acc[mt][nt] = MFMA16(af[mt], bf[nt], acc[mt][nt]);

        int tmp = b0; b0 = b1; b1 = b2; b2 = tmp;
    }
#undef GISSUE

    int rg = g * 4;
#pragma unroll
    for (int mt = 0; mt < MT; mt++)
#pragma unroll
        for (int nt = 0; nt < 4; nt++)
#pragma unroll
            for (int r = 0; r < 4; r++) {
                int row = m0 + wm + mt * 16 + rg + r;
                int col = n0 + wn + nt * 16 + ln;
                float v = acc[mt][nt][r];
                if (OUT_F16)
                    ((f16*)Cv)[(size_t)row * N + col] = (f16)v;
                else
                    ((float*)Cv)[(size_t)row * N + col] = v;
            }
}

// ---------------- flash attention v9: async-LDS staging, in-register P, split-k --------
// (verified rounds 6-10 -- unchanged, exactly the round-8 source)
__global__ __launch_bounds__(256, 2) void k_attn(const f16* __restrict__ QKV,
                                                 const f16* __restrict__ Vt,
                                                 f16* __restrict__ Opart,
                                                 float* __restrict__ Rsum) {
    __shared__ f16 Ks[2][64][64];
    __shared__ f16 Vs[2][64][64];  // V^T tile: [d][k]
    int bh = blockIdx.x, pi = blockIdx.y;  // pi 0..15
    int b = bh >> 4, h = bh & 15;
    int t = threadIdx.x, lane = t & 63, wq = t >> 6;
    int ln = lane & 15, g = lane >> 4, g8 = g * 8, rg = g * 4;
    int sx = ln & 7;  // read-side chunk xor

    int r0 = wq * 8 + (lane >> 3);        // phys row for instr 0 (0..31)
    int cp = lane & 7;
    int cl = (cp ^ (r0 & 7)) * 8;         // logical col (f16 elems) to fetch
    int gk0 = ((r0 & 16) >> 2) | ((r0 & 12) << 1) | (r0 & 3);  // glob(r0)
    const f16* Kb = QKV + (size_t)b * 2048 * 3072 + 1024 + h * 64;
    const f16* Vb = Vt + (size_t)bh * 64 * 2048;
    const f16* gK0 = Kb + (size_t)gk0 * 3072 + cl;
    const f16* gK1 = Kb + (size_t)(gk0 + 32) * 3072 + cl;
    const f16* gV0 = Vb + (size_t)r0 * 2048 + cl;
    const f16* gV1 = Vb + (size_t)(r0 + 32) * 2048 + cl;

    const float C_SCL = 0.18033688f;   // 0.125 * log2(e)
    const float C_MSK = -72.134752f;   // -50 * log2(e)
    f16x8 ones;
#pragma unroll
    for (int j = 0; j < 8; j++) ones[j] = (f16)1.f;

    int nk0 = 16 - pi;  // phase-0 tile count; total tiles always 17

#define ISSUE(bi, j)                                                      \
    do {                                                                  \
        int jj = (j);                                                     \
        int kt_ = (jj < nk0) ? jj : jj - nk0 + pi + 1;                    \
        size_t kO = (size_t)kt_ * 64;                                     \
        async16(&Ks[bi][wq * 8][0],      gK0 + kO * 3072);                \
        async16(&Ks[bi][32 + wq * 8][0], gK1 + kO * 3072);                \
        async16(&Vs[bi][wq * 8][0],      gV0 + kO);                       \
        async16(&Vs[bi][32 + wq * 8][0], gV1 + kO);                       \
    } while (0)

    ISSUE(0, 0);
    __syncthreads();  // barrier drains vmcnt -> tile 0 staged

    int i = 0;
    for (int phase = 0; phase < 2; phase++) {
        int qt  = phase ? pi : 15 - pi;
        int ktB = phase ? pi + 1 : 0;
        int ktE = phase ? 2 * pi + 2 : 16 - pi;
        int q0 = qt * 128;

        f16x8 bq[2][2];
#pragma unroll
        for (int nt = 0; nt < 2; nt++)
#pragma unroll
            for (int kd = 0; kd < 2; kd++)
                bq[nt][kd] = *(const f16x8*)(QKV +
                    (size_t)(b * 2048 + q0 + wq * 32 + nt * 16 + ln) * 3072 +
                    h * 64 + kd * 32 + g8);

        f32x4 oacc[2][4] = {};
        f32x4 osum[2] = {};

        for (int kt = ktB; kt < ktE; kt++, i++) {
            int cur = i & 1;
            int k0 = kt * 64;
            bool active = (k0 <= q0 + wq * 32 + 31);  // wave-uniform

            if (i + 1 < 17) ISSUE(cur ^ 1, i + 1);

            if (active) {
                f16x8 ak[2][4];
#pragma unroll
                for (int kd = 0; kd < 2; kd++)
#pragma unroll
                    for (int mt = 0; mt < 4; mt++)
                        ak[kd][mt] = *(const f16x8*)
                            &Ks[cur][mt * 16 + ln][((kd * 4 + g) ^ sx) * 8];
                f32x4 sacc[4][2] = {};
#pragma unroll
                for (int kd = 0; kd < 2; kd++)
#pragma unroll
                    for (int mt = 0; mt < 4; mt++)
#pragma unroll
                        for (int nt = 0; nt < 2; nt++)
                            sacc[mt][nt] = MFMA16(ak[kd][mt], bq[nt][kd], sacc[mt][nt]);

                bool needs_mask = (k0 + 63 > q0 + wq * 32);
                f16x8 ap[2][2];
#pragma unroll
                for (int nt = 0; nt < 2; nt++) {
                    int q = q0 + wq * 32 + nt * 16 + ln;
#pragma unroll
                    for (int mt = 0; mt < 4; mt++) {
                        int kb = mt >> 1, hi4 = (mt & 1) * 4;
#pragma unroll
                        for (int r = 0; r < 4; r++) {
                            float e;
                            if (needs_mask) {
                                int kk = k0 + kb * 32 + hi4 + 8 * g + r;
                                e = __builtin_amdgcn_exp2f(
                                    fmaf(sacc[mt][nt][r], C_SCL, (kk > q) ? C_MSK : 0.f));
                            } else {
                                e = __builtin_amdgcn_exp2f(sacc[mt][nt][r] * C_SCL);
                            }
                            ap[nt][kb][hi4 + r] = (f16)e;
                        }
                    }
                }

#pragma unroll
                for (int kk = 0; kk < 2; kk++) {
                    f16x8 bv[4];
#pragma unroll
                    for (int dt = 0; dt < 4; dt++)
                        bv[dt] = *(const f16x8*)
                            &Vs[cur][dt * 16 + ln][((kk * 4 + g) ^ sx) * 8];
#pragma unroll
                    for (int nt = 0; nt < 2; nt++) {
#pragma unroll
                        for (int dt = 0; dt < 4; dt++)
                            oacc[nt][dt] = MFMA16(ap[nt][kk], bv[dt], oacc[nt][dt]);
                        osum[nt] = MFMA16(ap[nt][kk], ones, osum[nt]);
                    }
                }
            }
            __syncthreads();  // drains tile i+1 staging; all waves done reading cur
        }

        int u = (bh * 16 + qt) * 2 + phase;
#pragma unroll
        for (int nt = 0; nt < 2; nt++)
#pragma unroll
            for (int r = 0; r < 4; r++) {
                float rs = osum[nt][r];
                float inv = __builtin_amdgcn_rcpf(fmaxf(rs, 1e-30f));
                int q = wq * 32 + nt * 16 + rg + r;
                if (ln == 0) Rsum[u * 128 + q] = rs;
#pragma unroll
                for (int dt = 0; dt < 4; dt++)
                    Opart[(size_t)u * 8192 + q * 64 + dt * 16 + ln] =
                        (f16)(oacc[nt][dt][r] * inv);
            }
    }
#undef ISSUE
}

// ---------------- merge split-k partials: O = (rs0*O0 + rs1*O1)/(rs0+rs1) ----------------
__global__ __launch_bounds__(256) void k_merge(const f16* __restrict__ Op,
                                               const float* __restrict__ Rs,
                                               f16* __restrict__ Ob) {
    int idx = blockIdx.x * 256 + threadIdx.x;  // 64bh*16qt*128q*8chunks = 1,048,576
    int d8 = idx & 7;
    int q  = (idx >> 3) & 127;
    int qt = (idx >> 10) & 15;
    int bh = idx >> 14;
    int b = bh >> 4, hd = bh & 15;
    int u0 = (bh * 16 + qt) * 2;
    float rs0 = Rs[u0 * 128 + q], rs1 = Rs[(u0 + 1) * 128 + q];
    float inv = __builtin_amdgcn_rcpf(rs0 + rs1);  // rs0 > 0 always (diagonal in half 0)
    f16x8 o0 = *(const f16x8*)(Op + (size_t)u0 * 8192 + q * 64 + d8 * 8);
    f16x8 o1 = *(const f16x8*)(Op + (size_t)(u0 + 1) * 8192 + q * 64 + d8 * 8);
    f16x8 o;
#pragma unroll
    for (int j = 0; j < 8; j++)
        o[j] = (f16)((rs0 * (float)o0[j] + rs1 * (float)o1[j]) * inv);
    *(f16x8*)(Ob + (size_t)(b * 2048 + qt * 128 + q) * 1024 + hd * 64 + d8 * 8) = o;
}

// ---------------- host launch ----------------
extern "C" void kernel_launch(void* const* d_in, const int* in_sizes, int n_in,
                              void* d_out, int out_size, void* d_ws, size_t ws_size,
                              hipStream_t stream) {
    const float* x = (const float*)d_in[0];
    const float* Wq = (const float*)d_in[1];
    const float* Wk = (const float*)d_in[2];
    const float* Wv = (const float*)d_in[3];
    const float* Wr = (const float*)d_in[4];
    float* out = (float*)d_out;

    f16* ws = (f16*)d_ws;
    f16* xb    = ws;                    // 8192*1024
    f16* Wqkvt = xb + 8388608;          // 3072*1024
    f16* Wrt   = Wqkvt + 3145728;       // 1024*1024
    f16* QKVb  = Wrt + 1048576;         // 8192*3072
    f16* Vtb   = QKVb + 25165824;       // 64bh * 64d * 2048s
    f16* Obuf  = Vtb + 8388608;         // 8192*1024
    f16* Opart = Obuf + 8388608;        // 2048 units * 128q * 64d
    float* Rsum = (float*)(Opart + 16777216);  // 2048 units * 128q

    k_prep<<<12288, 256, 0, stream>>>(x, Wq, Wk, Wv, Wr, xb, Wqkvt, Wrt);
    k_gemm_bt<true, 128><<<dim3(24, 64), 256, 0, stream>>>(xb, Wqkvt, QKVb,
                                                           8192, 3072, 1024);
    dim3 tb(32, 8);
    k_transpose_v<<<dim3(64, 2, 64), tb, 0, stream>>>(QKVb, Vtb);
    k_attn<<<dim3(64, 16), 256, 0, stream>>>(QKVb, Vtb, Opart, Rsum);
    k_merge<<<4096, 256, 0, stream>>>(Opart, Rsum, Obuf);
    k_gemm_bt<false, 64><<<dim3(8, 128), 256, 0, stream>>>(Obuf, Wrt, out,
                                                           8192, 1024, 1024);
}